// Round 2
// baseline (63210.309 us; speedup 1.0000x reference)
//
#include <hip/hip_runtime.h>
#include <math.h>

#define BB 256
#define TT 2048
#define DIN 64
#define HH 256

#define BR 32   // batch rows per WG
#define HU 8    // hidden units per WG
#define NC 32   // gate cols per WG = 4*HU

#define SW0 324 // Wl0 row stride (K=320 +4 pad)
#define SW1 516 // Wl1 row stride (K=512 +4 pad)

// LDS carve (floats)
#define OFF_WL0   0
#define OFF_WL1   (OFF_WL0 + NC*SW0)        // 10368
#define OFF_STAGE (OFF_WL1 + NC*SW1)        // 26880
#define OFF_GBUF  (OFF_STAGE + BR*256)      // 35072
#define OFF_B0    (OFF_GBUF + BR*36)        // 36224
#define OFF_B1    (OFF_B0 + 32)             // 36256
#define LDS_FLOATS (OFF_B1 + 32)            // 36288
#define LDS_BYTES  (LDS_FLOATS * 4)         // 145152

__device__ __forceinline__ float sigf(float v) {
    return 1.0f / (1.0f + __expf(-v));
}

__device__ __forceinline__ void group_barrier(unsigned* cnt, unsigned target) {
    __syncthreads();
    if (threadIdx.x == 0) {
        __hip_atomic_fetch_add(cnt, 1u, __ATOMIC_RELEASE, __HIP_MEMORY_SCOPE_AGENT);
        while (__hip_atomic_load(cnt, __ATOMIC_ACQUIRE, __HIP_MEMORY_SCOPE_AGENT) < target) {
            __builtin_amdgcn_s_sleep(1);
        }
    }
    __syncthreads();
}

__global__ __launch_bounds__(256, 1)
void lstm_persist(const float* __restrict__ x,
                  const float* __restrict__ Wih0, const float* __restrict__ Whh0,
                  const float* __restrict__ bih0, const float* __restrict__ bhh0,
                  const float* __restrict__ Wih1, const float* __restrict__ Whh1,
                  const float* __restrict__ bih1, const float* __restrict__ bhh1,
                  const float* __restrict__ Wd,   const float* __restrict__ bd,
                  float* __restrict__ out, float* __restrict__ hbase,
                  unsigned* __restrict__ counters)
{
    extern __shared__ float lds[];
    float* Wl0   = lds + OFF_WL0;    // [NC][SW0], col-major per gate-col
    float* Wl1   = lds + OFF_WL1;    // [NC][SW1]
    float* stage = lds + OFF_STAGE;  // [BR][256] flat
    float* gbuf  = lds + OFF_GBUF;   // [BR][36]
    float* bias0 = lds + OFF_B0;
    float* bias1 = lds + OFF_B1;

    const int w     = blockIdx.x;
    const int rb    = w & 7;    // row-group id (== XCD affinity hint)
    const int ug    = w >> 3;   // unit-group 0..31
    const int rbase = rb * BR;
    const int u0    = ug * HU;
    const int tid   = threadIdx.x;

    unsigned* cnt = counters + rb * 64;  // 256B-spaced counters

    float* h0b0 = hbase;
    float* h0b1 = hbase + 65536;
    float* h1b0 = hbase + 131072;
    float* h1b1 = hbase + 196608;
    float* h0b[2] = { h0b0, h0b1 };
    float* h1b[2] = { h1b0, h1b1 };

    // ---- load stationary weights into LDS ----
    for (int idx = tid; idx < NC * 320; idx += 256) {
        int c  = idx / 320, kk = idx % 320;
        int g  = (c >> 3) * HH + u0 + (c & 7);
        float v = (kk < 64) ? Wih0[g * 64 + kk] : Whh0[g * 256 + (kk - 64)];
        Wl0[c * SW0 + kk] = v;
    }
    for (int idx = tid; idx < NC * 512; idx += 256) {
        int c  = idx / 512, kk = idx % 512;
        int g  = (c >> 3) * HH + u0 + (c & 7);
        float v = (kk < 256) ? Wih1[g * 256 + kk] : Whh1[g * 256 + (kk - 256)];
        Wl1[c * SW1 + kk] = v;
    }
    if (tid < 32) {
        int g = (tid >> 3) * HH + u0 + (tid & 7);
        bias0[tid] = bih0[g] + bhh0[g];
        bias1[tid] = bih1[g] + bhh1[g];
    }
    // ---- zero my published h slots (ws is poisoned) ----
    {
        int r = tid >> 3, u = tid & 7;
        int off = (rbase + r) * HH + u0 + u;
        h0b0[off] = 0.f; h0b1[off] = 0.f; h1b0[off] = 0.f; h1b1[off] = 0.f;
    }
    unsigned epoch = 1;
    group_barrier(cnt, 32u * epoch);

    // compute mapping: col + 4-row tile
    const int cc = tid & 31;
    const int r0 = (tid >> 5) * 4;
    // update mapping: one (row, unit) per thread
    const int ur = tid >> 3, uu = tid & 7;
    const int urow = rbase + ur;

    float c0s = 0.f, c1s = 0.f;

    for (int k = 0; k <= TT; ++k) {
        // ---- stage h0(t=k-1) UNCONDITIONALLY (phase B at k needs it even when
        //      phase A's compute is skipped at k==TT — this was the round-1 bug) ----
        {
            const float4* src = reinterpret_cast<const float4*>(h0b[(k + 1) & 1] + rbase * HH);
            float4* dst = reinterpret_cast<float4*>(stage);
            #pragma unroll
            for (int j = 0; j < 8; ++j) {
                int f = tid + j * 256;
                dst[f] = src[f];
            }
        }
        __syncthreads();

        // ================= phase A: layer0 step t=k =================
        if (k < TT) {
            float b0 = bias0[cc];
            float acc[4] = { b0, b0, b0, b0 };
            const float* wrow = Wl0 + cc * SW0;
            // x part (K=64), x read direct from global (broadcast across lanes)
            {
                const float* xb = x + (size_t)(rbase + r0) * (TT * DIN) + (size_t)k * DIN;
                #pragma unroll 4
                for (int q = 0; q < 16; ++q) {
                    float4 wv = *reinterpret_cast<const float4*>(wrow + q * 4);
                    #pragma unroll
                    for (int i = 0; i < 4; ++i) {
                        float4 xv = *reinterpret_cast<const float4*>(xb + (size_t)i * (TT * DIN) + q * 4);
                        acc[i] += wv.x * xv.x + wv.y * xv.y + wv.z * xv.z + wv.w * xv.w;
                    }
                }
            }
            // h0 recurrent part (K=256) from LDS stage
            {
                const float* wh = wrow + 64;
                #pragma unroll 4
                for (int q = 0; q < 64; ++q) {
                    float4 wv = *reinterpret_cast<const float4*>(wh + q * 4);
                    #pragma unroll
                    for (int i = 0; i < 4; ++i) {
                        float4 hv = *reinterpret_cast<const float4*>(stage + (r0 + i) * 256 + q * 4);
                        acc[i] += wv.x * hv.x + wv.y * hv.y + wv.z * hv.z + wv.w * hv.w;
                    }
                }
            }
            #pragma unroll
            for (int i = 0; i < 4; ++i) gbuf[(r0 + i) * 36 + cc] = acc[i];
            __syncthreads();
            // elementwise cell update + publish h0(t=k)
            {
                float gi = gbuf[ur * 36 + uu];
                float gf = gbuf[ur * 36 + 8 + uu];
                float gg = gbuf[ur * 36 + 16 + uu];
                float go = gbuf[ur * 36 + 24 + uu];
                c0s = sigf(gf) * c0s + sigf(gi) * tanhf(gg);
                float h0n = sigf(go) * tanhf(c0s);
                h0b[k & 1][urow * HH + u0 + uu] = h0n;
            }
        }
        // ================= phase B: layer1 step t=k-1 =================
        if (k >= 1) {
            float b1 = bias1[cc];
            float acc[4] = { b1, b1, b1, b1 };
            const float* wrow = Wl1 + cc * SW1;
            // part 1: h0(t=k-1) still in stage
            {
                #pragma unroll 4
                for (int q = 0; q < 64; ++q) {
                    float4 wv = *reinterpret_cast<const float4*>(wrow + q * 4);
                    #pragma unroll
                    for (int i = 0; i < 4; ++i) {
                        float4 hv = *reinterpret_cast<const float4*>(stage + (r0 + i) * 256 + q * 4);
                        acc[i] += wv.x * hv.x + wv.y * hv.y + wv.z * hv.z + wv.w * hv.w;
                    }
                }
            }
            __syncthreads();  // part-1 stage reads done (also covers phase-A gbuf reads)
            // restage h1(t=k-2)
            {
                const float4* src = reinterpret_cast<const float4*>(h1b[(k + 1) & 1] + rbase * HH);
                float4* dst = reinterpret_cast<float4*>(stage);
                #pragma unroll
                for (int j = 0; j < 8; ++j) {
                    int f = tid + j * 256;
                    dst[f] = src[f];
                }
            }
            __syncthreads();
            // part 2: h1 recurrent
            {
                const float* wh = wrow + 256;
                #pragma unroll 4
                for (int q = 0; q < 64; ++q) {
                    float4 wv = *reinterpret_cast<const float4*>(wh + q * 4);
                    #pragma unroll
                    for (int i = 0; i < 4; ++i) {
                        float4 hv = *reinterpret_cast<const float4*>(stage + (r0 + i) * 256 + q * 4);
                        acc[i] += wv.x * hv.x + wv.y * hv.y + wv.z * hv.z + wv.w * hv.w;
                    }
                }
            }
            #pragma unroll
            for (int i = 0; i < 4; ++i) gbuf[(r0 + i) * 36 + cc] = acc[i];
            __syncthreads();
            {
                float gi = gbuf[ur * 36 + uu];
                float gf = gbuf[ur * 36 + 8 + uu];
                float gg = gbuf[ur * 36 + 16 + uu];
                float go = gbuf[ur * 36 + 24 + uu];
                c1s = sigf(gf) * c1s + sigf(gi) * tanhf(gg);
                float h1n = sigf(go) * tanhf(c1s);
                h1b[k & 1][urow * HH + u0 + uu] = h1n;
            }
        }
        ++epoch;
        group_barrier(cnt, 32u * epoch);  // release h(t=k) / h1(t=k-1) to the row-group
    }

    // ================= dense head: out = h1(T-1) @ Wd^T + bd =================
    // h1(T-1) published at k=TT (even) -> h1b[0]
    if (ug == 0 && tid < 64) {
        int r = tid >> 1, j = tid & 1;
        const float4* hv = reinterpret_cast<const float4*>(h1b0 + (rbase + r) * HH);
        const float4* wv = reinterpret_cast<const float4*>(Wd + j * HH);
        float a = bd[j];
        #pragma unroll 4
        for (int q = 0; q < 64; ++q) {
            float4 h4 = hv[q], w4 = wv[q];
            a += h4.x * w4.x + h4.y * w4.y + h4.z * w4.z + h4.w * w4.w;
        }
        out[(rbase + r) * 2 + j] = a;
    }
}

extern "C" void kernel_launch(void* const* d_in, const int* in_sizes, int n_in,
                              void* d_out, int out_size, void* d_ws, size_t ws_size,
                              hipStream_t stream) {
    const float* x    = (const float*)d_in[0];
    const float* Wih0 = (const float*)d_in[1];
    const float* Whh0 = (const float*)d_in[2];
    const float* bih0 = (const float*)d_in[3];
    const float* bhh0 = (const float*)d_in[4];
    const float* Wih1 = (const float*)d_in[5];
    const float* Whh1 = (const float*)d_in[6];
    const float* bih1 = (const float*)d_in[7];
    const float* bhh1 = (const float*)d_in[8];
    const float* Wd   = (const float*)d_in[9];
    const float* bd   = (const float*)d_in[10];
    float* out = (float*)d_out;

    unsigned* counters = (unsigned*)d_ws;                 // 4KB of barrier counters
    float* hbase = (float*)((char*)d_ws + 4096);          // 1MB of h double-buffers

    // zero barrier counters every launch (deterministic across graph replays)
    hipMemsetAsync(d_ws, 0, 4096, stream);

    hipFuncSetAttribute((const void*)lstm_persist,
                        hipFuncAttributeMaxDynamicSharedMemorySize, LDS_BYTES);

    void* args[] = { (void*)&x, (void*)&Wih0, (void*)&Whh0, (void*)&bih0, (void*)&bhh0,
                     (void*)&Wih1, (void*)&Whh1, (void*)&bih1, (void*)&bhh1,
                     (void*)&Wd, (void*)&bd, (void*)&out, (void*)&hbase, (void*)&counters };
    hipLaunchCooperativeKernel((const void*)lstm_persist, dim3(256), dim3(256),
                               args, LDS_BYTES, stream);
}

// Round 4
// 16177.687 us; speedup vs baseline: 3.9073x; 3.9073x over previous
//
#include <hip/hip_runtime.h>
#include <math.h>

#define TT 2048
#define DIN 64
#define HH 256
#define BR 32

typedef __attribute__((ext_vector_type(8))) short bf16x8;
typedef __attribute__((ext_vector_type(4))) float f32x4;
typedef unsigned short u16;

// ---- LDS layout (shorts region, then floats region) ----
#define XS_STR 72    // x stage row stride (64 + 8 pad)
#define HS_STR 264   // h stage row stride (256 + 8 pad)
#define GB_STR 36    // gate buffer row stride (32 + 4 pad)

#define OFF_XS_HI  0
#define OFF_XS_LO  (OFF_XS_HI + 32*XS_STR)     // 2304
#define OFF_HS0_HI (OFF_XS_LO + 32*XS_STR)     // 4608
#define OFF_HS0_LO (OFF_HS0_HI + 32*HS_STR)    // 13056
#define OFF_HS1_HI (OFF_HS0_LO + 32*HS_STR)    // 21504
#define OFF_HS1_LO (OFF_HS1_HI + 32*HS_STR)    // 29952
#define OFF_W0LO   (OFF_HS1_LO + 32*HS_STR)    // 38400  (1280 frags * 8)
#define OFF_W1LO   (OFF_W0LO + 1280*8)         // 48640  (2048 frags * 8)
#define SH_SHORTS  (OFF_W1LO + 2048*8)         // 65024 shorts
#define SH_BYTES   (SH_SHORTS*2)               // 130048 B
#define LDS_BYTES  (SH_BYTES + 2368*4)         // +gb0/gb1/biases = 139520 B

__device__ __forceinline__ u16 f2bf(float f){
    unsigned u = __builtin_bit_cast(unsigned, f);
    u += 0x7fffu + ((u >> 16) & 1u);           // RNE to bf16
    return (u16)(u >> 16);
}
__device__ __forceinline__ float bf2f(u16 h){
    unsigned u = ((unsigned)h) << 16;
    return __builtin_bit_cast(float, u);
}
__device__ __forceinline__ float sigf(float v){ return 1.0f/(1.0f+__expf(-v)); }

__device__ __forceinline__ void group_barrier(unsigned* cnt, unsigned target){
    __syncthreads();
    if (threadIdx.x == 0) {
        __hip_atomic_fetch_add(cnt, 1u, __ATOMIC_RELEASE, __HIP_MEMORY_SCOPE_AGENT);
        while (__hip_atomic_load(cnt, __ATOMIC_ACQUIRE, __HIP_MEMORY_SCOPE_AGENT) < target)
            __builtin_amdgcn_s_sleep(1);
    }
    __syncthreads();
}

__device__ __forceinline__ void split8(float4 a, float4 b, bf16x8& hi, bf16x8& lo){
    float v[8] = {a.x,a.y,a.z,a.w,b.x,b.y,b.z,b.w};
    #pragma unroll
    for (int j=0;j<8;++j){
        u16 h = f2bf(v[j]);
        hi[j] = (short)h;
        lo[j] = (short)f2bf(v[j] - bf2f(h));
    }
}

__global__ __launch_bounds__(256, 1)
void lstm_mfma(const float* __restrict__ x,
               const float* __restrict__ Wih0, const float* __restrict__ Whh0,
               const float* __restrict__ bih0, const float* __restrict__ bhh0,
               const float* __restrict__ Wih1, const float* __restrict__ Whh1,
               const float* __restrict__ bih1, const float* __restrict__ bhh1,
               const float* __restrict__ Wd,   const float* __restrict__ bd,
               float* __restrict__ out, u16* __restrict__ hb,
               unsigned* __restrict__ counters)
{
    extern __shared__ char smem[];
    short* sh  = (short*)smem;
    float* sf  = (float*)(smem + SH_BYTES);
    float* gb0 = sf;             // [32][36]
    float* gb1 = sf + 1152;      // [32][36]
    float* b0s = sf + 2304;      // [32]
    float* b1s = sf + 2336;      // [32]

    const int tid = threadIdx.x;
    const int w   = blockIdx.x;
    const int rb  = w & 7;      // row-group (XCD affinity)
    const int ug  = w >> 3;     // unit-group 0..31
    const int rbase = rb * BR;
    const int u0  = ug * 8;

    unsigned* cnt = counters + rb * 64;

    // h planes in ws (u16): h0hi[2] h0lo[2] h1hi[2] h1lo[2], each 65536
    // bases: h0hi=0, h0lo=131072, h1hi=262144, h1lo=393216 (+parity*65536)

    // ---- per-lane MFMA ids ----
    const int l  = tid & 63;
    const int wv = tid >> 6;          // wave 0..3
    const int mt = wv >> 1, nt = wv & 1;
    const int c  = l & 15, ks = l >> 4;
    const int gbx = nt*2 + (c >> 3);  // gate block (i,f | g,o by nt)
    const int g   = gbx*256 + u0 + (c & 7);

    // ---- stationary HI weight fragments in registers ----
    bf16x8 w0h[10];
    #pragma unroll
    for (int kt = 0; kt < 10; ++kt) {
        int k = kt*32 + ks*8;
        const float* p = (k < 64) ? (Wih0 + (size_t)g*64 + k)
                                  : (Whh0 + (size_t)g*256 + (k - 64));
        bf16x8 hi_, lo_;
        split8(*(const float4*)p, *(const float4*)(p+4), hi_, lo_);
        w0h[kt] = hi_;
    }
    bf16x8 w1h[16];
    #pragma unroll
    for (int kt = 0; kt < 16; ++kt) {
        int k = kt*32 + ks*8;
        const float* p = (k < 256) ? (Wih1 + (size_t)g*256 + k)
                                   : (Whh1 + (size_t)g*256 + (k - 256));
        bf16x8 hi_, lo_;
        split8(*(const float4*)p, *(const float4*)(p+4), hi_, lo_);
        w1h[kt] = hi_;
    }
    // ---- LO weight fragments into LDS, fragment order [kt][nt][ks][c][8] ----
    for (int f = tid; f < 1280; f += 256) {
        int c_ = f & 15, ks_ = (f>>4)&3, nt_ = (f>>6)&1, kt_ = f>>7;
        int g_ = (nt_*2 + (c_>>3))*256 + u0 + (c_&7);
        int k_ = kt_*32 + ks_*8;
        const float* p = (k_ < 64) ? (Wih0 + (size_t)g_*64 + k_)
                                   : (Whh0 + (size_t)g_*256 + (k_ - 64));
        bf16x8 hi_, lo_;
        split8(*(const float4*)p, *(const float4*)(p+4), hi_, lo_);
        *(bf16x8*)(sh + OFF_W0LO + f*8) = lo_;
    }
    for (int f = tid; f < 2048; f += 256) {
        int c_ = f & 15, ks_ = (f>>4)&3, nt_ = (f>>6)&1, kt_ = f>>7;
        int g_ = (nt_*2 + (c_>>3))*256 + u0 + (c_&7);
        int k_ = kt_*32 + ks_*8;
        const float* p = (k_ < 256) ? (Wih1 + (size_t)g_*256 + k_)
                                    : (Whh1 + (size_t)g_*256 + (k_ - 256));
        bf16x8 hi_, lo_;
        split8(*(const float4*)p, *(const float4*)(p+4), hi_, lo_);
        *(bf16x8*)(sh + OFF_W1LO + f*8) = lo_;
    }

    if (tid < 32) {
        int gg_ = (tid >> 3)*256 + u0 + (tid & 7);
        b0s[tid] = bih0[gg_] + bhh0[gg_];
        b1s[tid] = bih1[gg_] + bhh1[gg_];
    }
    // zero my h slots in all planes/parities (ws poisoned)
    {
        int zr = tid >> 3, zu = tid & 7;
        size_t off = (size_t)(rbase + zr)*HH + u0 + zu;
        hb[off] = 0; hb[65536 + off] = 0;
        hb[131072 + off] = 0; hb[196608 + off] = 0;
        hb[262144 + off] = 0; hb[327680 + off] = 0;
        hb[393216 + off] = 0; hb[458752 + off] = 0;
    }
    // stage x(0)
    {
        int xr = tid >> 3, xk = (tid & 7)*8;
        const float* xp = x + (size_t)(rbase + xr)*(TT*DIN) + xk;
        bf16x8 xh, xl;
        split8(*(const float4*)xp, *(const float4*)(xp+4), xh, xl);
        *(bf16x8*)(sh + OFF_XS_HI + xr*XS_STR + xk) = xh;
        *(bf16x8*)(sh + OFF_XS_LO + xr*XS_STR + xk) = xl;
    }
    unsigned epoch = 1;
    group_barrier(cnt, 32u*epoch);

    // A-frag LDS base pointers (lane holds row = mt*16 + c, k-run = ks*8)
    const int arow = mt*16 + c;
    const short* axh = sh + OFF_XS_HI  + arow*XS_STR + ks*8;
    const short* axl = sh + OFF_XS_LO  + arow*XS_STR + ks*8;
    const short* a0h = sh + OFF_HS0_HI + arow*HS_STR + ks*8;
    const short* a0l = sh + OFF_HS0_LO + arow*HS_STR + ks*8;
    const short* a1h = sh + OFF_HS1_HI + arow*HS_STR + ks*8;
    const short* a1l = sh + OFF_HS1_LO + arow*HS_STR + ks*8;
    // LO weight fragment lane pointers (stride 1024 shorts per kt)
    const short* b0lo = sh + OFF_W0LO + (nt*64 + ks*16 + c)*8;
    const short* b1lo = sh + OFF_W1LO + (nt*64 + ks*16 + c)*8;
    // D-tile -> gate buffer write pointers
    float* gw0 = gb0 + (mt*16 + ks*4)*GB_STR + nt*16 + c;
    float* gw1 = gb1 + (mt*16 + ks*4)*GB_STR + nt*16 + c;
    // cell-update mapping
    const int ur = tid >> 3, uu = tid & 7;
    const size_t poff = (size_t)(rbase + ur)*HH + u0 + uu;

    float c0s = 0.f, c1s = 0.f;

    for (int k = 0; k <= TT; ++k) {
        // ---- stage h0(k-1), h1(k-2) from global planes (parity rd) ----
        {
            const unsigned rdo = ((k + 1) & 1) * 65536u;
            const u16* s0h = hb + rdo;
            const u16* s0l = hb + 131072 + rdo;
            const u16* s1h = hb + 262144 + rdo;
            const u16* s1l = hb + 393216 + rdo;
            #pragma unroll
            for (int j = 0; j < 4; ++j) {
                int cid = tid + j*256;
                int hr = cid >> 5, hk = (cid & 31)*8;
                size_t goff = (size_t)(rbase + hr)*HH + hk;
                int loff = hr*HS_STR + hk;
                *(uint4*)(sh + OFF_HS0_HI + loff) = *(const uint4*)(s0h + goff);
                *(uint4*)(sh + OFF_HS0_LO + loff) = *(const uint4*)(s0l + goff);
                *(uint4*)(sh + OFF_HS1_HI + loff) = *(const uint4*)(s1h + goff);
                *(uint4*)(sh + OFF_HS1_LO + loff) = *(const uint4*)(s1l + goff);
            }
        }
        __syncthreads();

        // ---- phase A: layer0 step t=k ----
        if (k < TT) {
            f32x4 ac[4] = {};
            #pragma unroll
            for (int kt = 0; kt < 10; ++kt) {
                const short* ph = (kt < 2) ? (axh + kt*32) : (a0h + (kt-2)*32);
                const short* pl = (kt < 2) ? (axl + kt*32) : (a0l + (kt-2)*32);
                bf16x8 ah = *(const bf16x8*)ph;
                bf16x8 al = *(const bf16x8*)pl;
                bf16x8 wl = *(const bf16x8*)(b0lo + kt*1024);
                const int q = kt & 3;
                ac[q] = __builtin_amdgcn_mfma_f32_16x16x32_bf16(ah, w0h[kt], ac[q], 0,0,0);
                ac[q] = __builtin_amdgcn_mfma_f32_16x16x32_bf16(al, w0h[kt], ac[q], 0,0,0);
                ac[q] = __builtin_amdgcn_mfma_f32_16x16x32_bf16(ah, wl,      ac[q], 0,0,0);
            }
            f32x4 aa = (ac[0] + ac[1]) + (ac[2] + ac[3]);
            gw0[0]        = aa[0];
            gw0[GB_STR]   = aa[1];
            gw0[2*GB_STR] = aa[2];
            gw0[3*GB_STR] = aa[3];
        }
        // ---- phase B: layer1 step t=k-1 ----
        if (k >= 1) {
            f32x4 ac[4] = {};
            #pragma unroll
            for (int kt = 0; kt < 16; ++kt) {
                const short* ph = (kt < 8) ? (a0h + kt*32) : (a1h + (kt-8)*32);
                const short* pl = (kt < 8) ? (a0l + kt*32) : (a1l + (kt-8)*32);
                bf16x8 ah = *(const bf16x8*)ph;
                bf16x8 al = *(const bf16x8*)pl;
                bf16x8 wl = *(const bf16x8*)(b1lo + kt*1024);
                const int q = kt & 3;
                ac[q] = __builtin_amdgcn_mfma_f32_16x16x32_bf16(ah, w1h[kt], ac[q], 0,0,0);
                ac[q] = __builtin_amdgcn_mfma_f32_16x16x32_bf16(al, w1h[kt], ac[q], 0,0,0);
                ac[q] = __builtin_amdgcn_mfma_f32_16x16x32_bf16(ah, wl,      ac[q], 0,0,0);
            }
            f32x4 aa = (ac[0] + ac[1]) + (ac[2] + ac[3]);
            gw1[0]        = aa[0];
            gw1[GB_STR]   = aa[1];
            gw1[2*GB_STR] = aa[2];
            gw1[3*GB_STR] = aa[3];
        }
        __syncthreads();

        // ---- cell updates + publish (hi/lo bf16 planes, parity wr) ----
        const unsigned wro = (k & 1) * 65536u;
        if (k < TT) {
            float gi = gb0[ur*GB_STR + uu]      + b0s[uu];
            float gf = gb0[ur*GB_STR + 8 + uu]  + b0s[8+uu];
            float gg = gb0[ur*GB_STR + 16 + uu] + b0s[16+uu];
            float go = gb0[ur*GB_STR + 24 + uu] + b0s[24+uu];
            c0s = sigf(gf)*c0s + sigf(gi)*tanhf(gg);
            float hn = sigf(go)*tanhf(c0s);
            u16 hh_ = f2bf(hn);
            u16 hl_ = f2bf(hn - bf2f(hh_));
            (hb + wro)[poff]          = hh_;
            (hb + 131072 + wro)[poff] = hl_;
        }
        if (k >= 1) {
            float gi = gb1[ur*GB_STR + uu]      + b1s[uu];
            float gf = gb1[ur*GB_STR + 8 + uu]  + b1s[8+uu];
            float gg = gb1[ur*GB_STR + 16 + uu] + b1s[16+uu];
            float go = gb1[ur*GB_STR + 24 + uu] + b1s[24+uu];
            c1s = sigf(gf)*c1s + sigf(gi)*tanhf(gg);
            float hn = sigf(go)*tanhf(c1s);
            u16 hh_ = f2bf(hn);
            u16 hl_ = f2bf(hn - bf2f(hh_));
            (hb + 262144 + wro)[poff] = hh_;
            (hb + 393216 + wro)[poff] = hl_;
        }
        // ---- prefetch-stage x(k+1) (overlaps publish + barrier) ----
        if (k + 1 < TT) {
            int xr = tid >> 3, xk = (tid & 7)*8;
            const float* xp = x + (size_t)(rbase + xr)*(TT*DIN) + (size_t)(k+1)*DIN + xk;
            bf16x8 xh, xl;
            split8(*(const float4*)xp, *(const float4*)(xp+4), xh, xl);
            *(bf16x8*)(sh + OFF_XS_HI + xr*XS_STR + xk) = xh;
            *(bf16x8*)(sh + OFF_XS_LO + xr*XS_STR + xk) = xl;
        }
        ++epoch;
        group_barrier(cnt, 32u*epoch);
    }

    // ---- dense head: out = h1(T-1) @ Wd^T + bd ; h1(T-1) in parity-0 planes ----
    if (ug == 0 && tid < 64) {
        int r = tid >> 1, j = tid & 1;
        const u16* hhp = hb + 262144 + (size_t)(rbase + r)*HH;
        const u16* hlp = hb + 393216 + (size_t)(rbase + r)*HH;
        const float* wdp = Wd + j*HH;
        float a = bd[j];
        #pragma unroll 4
        for (int q = 0; q < HH; ++q)
            a += (bf2f(hhp[q]) + bf2f(hlp[q])) * wdp[q];
        out[(rbase + r)*2 + j] = a;
    }
}

extern "C" void kernel_launch(void* const* d_in, const int* in_sizes, int n_in,
                              void* d_out, int out_size, void* d_ws, size_t ws_size,
                              hipStream_t stream) {
    const float* x    = (const float*)d_in[0];
    const float* Wih0 = (const float*)d_in[1];
    const float* Whh0 = (const float*)d_in[2];
    const float* bih0 = (const float*)d_in[3];
    const float* bhh0 = (const float*)d_in[4];
    const float* Wih1 = (const float*)d_in[5];
    const float* Whh1 = (const float*)d_in[6];
    const float* bih1 = (const float*)d_in[7];
    const float* bhh1 = (const float*)d_in[8];
    const float* Wd   = (const float*)d_in[9];
    const float* bd   = (const float*)d_in[10];
    float* out = (float*)d_out;

    unsigned* counters = (unsigned*)d_ws;               // 4 KB barrier counters
    u16* hb = (u16*)((char*)d_ws + 4096);               // 1 MB h hi/lo planes

    hipMemsetAsync(d_ws, 0, 4096, stream);

    hipFuncSetAttribute((const void*)lstm_mfma,
                        hipFuncAttributeMaxDynamicSharedMemorySize, LDS_BYTES);

    // Plain launch: co-residency is structurally guaranteed (139.5 KB LDS/WG
    // forces exactly 1 block/CU; grid == 256 == CU count), and the in-kernel
    // barrier is homemade atomics — no cooperative-launch semantics needed.
    lstm_mfma<<<dim3(256), dim3(256), LDS_BYTES, stream>>>(
        x, Wih0, Whh0, bih0, bhh0, Wih1, Whh1, bih1, bhh1,
        Wd, bd, out, hb, counters);
}